// Round 2
// baseline (568.212 us; speedup 1.0000x reference)
//
#include <hip/hip_runtime.h>
#include <math.h>

// KGATConv: N=50000, E=800000, D=64, R=16, fp32.
// R8: (1) k_proj stores bounced through LDS -> coalesced 16B uint4 stores
//     (was 32B-granular scalar bf16 stores).
//     (2) CSR build: k_hist's atomic return IS the within-segment rank;
//     k_fill eliminated (src_s write folded into k_att, p = off[dst]+rank).
//     Scan merged to 2 kernels. 9 -> 7 dispatches, one 800k-atomic pass gone.
//     (3) k_aggB stages W1/W2 in LDS (frees L1 for nfeat gathers).

#define DIM 64
#define PA 72

typedef _Float16 half8 __attribute__((ext_vector_type(8)));
typedef float f32x4 __attribute__((ext_vector_type(4)));
typedef unsigned int u32x4 __attribute__((ext_vector_type(4)));

__device__ __forceinline__ float4 f4zero() { return make_float4(0.f, 0.f, 0.f, 0.f); }

__device__ __forceinline__ unsigned short f2bf(float x) {
    unsigned u = __float_as_uint(x);
    u += 0x7FFFu + ((u >> 16) & 1u);   // RNE
    return (unsigned short)(u >> 16);
}

__device__ __forceinline__ float fast_tanh(float x) {
    float ex = __expf(2.0f * x);
    return 1.0f - 2.0f / (ex + 1.0f);
}

// unpack 8 bf16 (in a u32x4) to fp32
__device__ __forceinline__ void bf8up(u32x4 u, float* f) {
    f[0] = __uint_as_float(u[0] << 16);
    f[1] = __uint_as_float(u[0] & 0xFFFF0000u);
    f[2] = __uint_as_float(u[1] << 16);
    f[3] = __uint_as_float(u[1] & 0xFFFF0000u);
    f[4] = __uint_as_float(u[2] << 16);
    f[5] = __uint_as_float(u[2] & 0xFFFF0000u);
    f[6] = __uint_as_float(u[3] << 16);
    f[7] = __uint_as_float(u[3] & 0xFFFF0000u);
}

// ---------------------------------------------------------------------------
// proj[r,n,:] = bf16( nfeat[n,:] @ relW[r,:,:] ) via mfma_f32_16x16x32_f16
// A-tile + fragments loaded once; loop over R relations. Output bounced
// through LDS (reusing shA) so global stores are coalesced 16B chunks.
// ---------------------------------------------------------------------------
__global__ __launch_bounds__(256) void k_proj(const float* __restrict__ nfeat,
                                              const float* __restrict__ relW,
                                              unsigned short* __restrict__ proj,
                                              int N, int R) {
    __shared__ _Float16 shA[64 * PA];
    __shared__ _Float16 shB[64 * PA];
    unsigned short* shSt = (unsigned short*)shA;   // store-staging (shA dead after frag load)

    const int tx = threadIdx.x;
    const int n0 = blockIdx.x * 64;

    const float4* nf4 = (const float4*)(nfeat + (size_t)n0 * DIM);
#pragma unroll
    for (int i = 0; i < 4; ++i) {
        int idx = tx + 256 * i;
        int row = idx >> 4, c = idx & 15;
        float4 v = (n0 + row < N) ? nf4[idx] : f4zero();
        _Float16* p = &shA[row * PA + c * 4];
        p[0] = (_Float16)v.x; p[1] = (_Float16)v.y;
        p[2] = (_Float16)v.z; p[3] = (_Float16)v.w;
    }
    __syncthreads();

    const int w = tx >> 6;
    const int lane = tx & 63;
    const int lm = lane & 15;
    const int lq = lane >> 4;
    const int m0 = w * 16;

    // A fragments are relation-independent: load once.
    half8 a0 = *(const half8*)&shA[(m0 + lm) * PA + 0 * 32 + lq * 8];
    half8 a1 = *(const half8*)&shA[(m0 + lm) * PA + 1 * 32 + lq * 8];

    for (int r = 0; r < R; ++r) {
        __syncthreads();   // prev iter's shB mfma-reads + shSt store-reads complete
        const float4* Wr4 = (const float4*)(relW + (size_t)r * DIM * DIM);
#pragma unroll
        for (int i = 0; i < 4; ++i) {
            int idx = tx + 256 * i;
            int d = idx >> 4, c = (idx & 15) * 4;
            float4 v = Wr4[idx];
            shB[(c + 0) * PA + d] = (_Float16)v.x;
            shB[(c + 1) * PA + d] = (_Float16)v.y;
            shB[(c + 2) * PA + d] = (_Float16)v.z;
            shB[(c + 3) * PA + d] = (_Float16)v.w;
        }
        __syncthreads();

        f32x4 acc[4];
#pragma unroll
        for (int ct = 0; ct < 4; ++ct) {
            half8 b0 = *(const half8*)&shB[(ct * 16 + lm) * PA + 0 * 32 + lq * 8];
            half8 b1 = *(const half8*)&shB[(ct * 16 + lm) * PA + 1 * 32 + lq * 8];
            f32x4 c = {0.f, 0.f, 0.f, 0.f};
            c = __builtin_amdgcn_mfma_f32_16x16x32_f16(a0, b0, c, 0, 0, 0);
            c = __builtin_amdgcn_mfma_f32_16x16x32_f16(a1, b1, c, 0, 0, 0);
            acc[ct] = c;
        }

        // stage bf16 result in LDS (row stride 72 ushort -> 144B, 16B aligned)
#pragma unroll
        for (int ct = 0; ct < 4; ++ct) {
#pragma unroll
            for (int i = 0; i < 4; ++i) {
                int row = m0 + lq * 4 + i;
                int col = ct * 16 + lm;
                shSt[row * PA + col] = f2bf(acc[ct][i]);
            }
        }
        __syncthreads();

        // coalesced stores: 512 x 16B chunks, 2 per thread; wave covers 1KB
        unsigned short* projR = proj + ((size_t)r * N + n0) * DIM;
#pragma unroll
        for (int k = 0; k < 2; ++k) {
            int chunk = tx + k * 256;
            int row = chunk >> 3, cc = chunk & 7;
            uint4 v = *(const uint4*)&shSt[row * PA + cc * 8];
            if (n0 + row < N)
                *(uint4*)&projR[(size_t)row * DIM + cc * 8] = v;
        }
    }
}

// ---------------------------------------------------------------------------
// CSR build: k_hist's atomic return value is the within-segment rank ->
// no second atomic pass, no cursor array, no fill kernel.
// ---------------------------------------------------------------------------
__global__ __launch_bounds__(256) void k_hist(const int* __restrict__ dst,
                                              int* __restrict__ deg,
                                              int* __restrict__ rank, int E) {
    int e = blockIdx.x * 256 + threadIdx.x;
    if (e < E) rank[e] = atomicAdd(&deg[dst[e]], 1);
}

// per-block inclusive scan of deg; epart = exclusive-within-block, bsum = block total
__global__ __launch_bounds__(256) void k_scan1(const int* __restrict__ deg,
                                               int* __restrict__ epart,
                                               int* __restrict__ bsum, int N) {
    __shared__ int sh[256];
    int i = blockIdx.x * 256 + threadIdx.x;
    int t = threadIdx.x;
    int v = (i < N) ? deg[i] : 0;
    sh[t] = v;
    __syncthreads();
#pragma unroll
    for (int d = 1; d < 256; d <<= 1) {
        int o = (t >= d) ? sh[t - d] : 0;
        __syncthreads();
        sh[t] += o;
        __syncthreads();
    }
    if (i < N) epart[i] = sh[t] - v;
    if (t == 255) bsum[blockIdx.x] = sh[255];
}

// single block: scan block sums, then add to epart -> off. 1024 threads.
__global__ __launch_bounds__(1024) void k_scan2(const int* __restrict__ epart,
                                                const int* __restrict__ bsum,
                                                int nb,
                                                int* __restrict__ off,
                                                int N, int E) {
    __shared__ int bx[256];
    int t = threadIdx.x;
    int v = 0;
    if (t < 256) {
        v = (t < nb) ? bsum[t] : 0;
        bx[t] = v;
    }
    __syncthreads();
#pragma unroll
    for (int d = 1; d < 256; d <<= 1) {
        int o = 0;
        if (t < 256 && t >= d) o = bx[t - d];
        __syncthreads();
        if (t < 256) bx[t] += o;
        __syncthreads();
    }
    if (t < 256) bx[t] -= v;   // exclusive block prefix
    __syncthreads();
    for (int i = t; i < N; i += 1024)
        off[i] = epart[i] + bx[i >> 8];
    if (t == 0) off[N] = E;
}

// ---------------------------------------------------------------------------
// Attention, 8 threads per edge. p = off[dst] + rank (atomic-free slot).
// sub0 writes att_s[p]; sub1 writes src_s[p] (absorbs the old k_fill).
// efeat streamed non-temporally to protect L3 residency of proj.
// ---------------------------------------------------------------------------
__global__ __launch_bounds__(256) void k_att(const unsigned short* __restrict__ proj,
                                             const float* __restrict__ efeat,
                                             const int* __restrict__ src,
                                             const int* __restrict__ dst,
                                             const int* __restrict__ etype,
                                             const int* __restrict__ rank,
                                             const int* __restrict__ off,
                                             float* __restrict__ att_s,
                                             int* __restrict__ src_s,
                                             int N, int E) {
    int t = blockIdx.x * 256 + threadIdx.x;
    int e = t >> 3;
    int sub = t & 7;
    if (e >= E) return;
    int s = src[e], d = dst[e], r = etype[e];

    const u32x4* tp = (const u32x4*)(proj + ((size_t)((unsigned)(r * N + s))) * DIM) + sub;
    const u32x4* hp = (const u32x4*)(proj + ((size_t)((unsigned)(r * N + d))) * DIM) + sub;
    const f32x4* ef = (const f32x4*)(efeat + (size_t)e * DIM) + sub * 2;

    u32x4 tu = *tp;
    u32x4 hu = *hp;
    f32x4 efa = __builtin_nontemporal_load(ef);
    f32x4 efb = __builtin_nontemporal_load(ef + 1);

    float tf[8], hf[8];
    bf8up(tu, tf);
    bf8up(hu, hf);
    float ev[8] = {efa[0], efa[1], efa[2], efa[3], efb[0], efb[1], efb[2], efb[3]};

    float dotv = 0.f;
#pragma unroll
    for (int i = 0; i < 8; ++i)
        dotv = fmaf(tf[i], fast_tanh(hf[i] + ev[i]), dotv);

    // reduce across the 8-lane group (all lanes end with the sum)
    dotv += __shfl_xor(dotv, 1);
    dotv += __shfl_xor(dotv, 2);
    dotv += __shfl_xor(dotv, 4);

    int p = off[d] + rank[e];
    if (sub == 0) att_s[p] = dotv;
    if (sub == 1) src_s[p] = s;
}

// ---------------------------------------------------------------------------
// Per-node softmax + aggregation + bi-interaction. Wave per node; W1/W2
// staged in LDS once per block (frees L1 for the nfeat gathers).
// ---------------------------------------------------------------------------
__global__ __launch_bounds__(256) void k_aggB(const float* __restrict__ att_s,
                                              const int* __restrict__ src_s,
                                              const float* __restrict__ nfeat,
                                              const int* __restrict__ off,
                                              const float* __restrict__ W1,
                                              const float* __restrict__ W2,
                                              float* __restrict__ hn,
                                              float* __restrict__ out,
                                              int N) {
    __shared__ float shW[2][DIM * DIM];
    const int tx = threadIdx.x;
    {
        const float4* w14 = (const float4*)W1;
        const float4* w24 = (const float4*)W2;
        float4* s0 = (float4*)shW[0];
        float4* s1 = (float4*)shW[1];
#pragma unroll
        for (int i = 0; i < 4; ++i) {
            s0[tx + 256 * i] = w14[tx + 256 * i];
            s1[tx + 256 * i] = w24[tx + 256 * i];
        }
    }
    __syncthreads();

    const int node = blockIdx.x * 4 + (tx >> 6);
    if (node >= N) return;
    const int lane = tx & 63;

    const int jb = off[node];
    const int je = off[node + 1];

    // exact segment max (edge-parallel, coalesced)
    float m = -INFINITY;
    for (int j0 = jb; j0 < je; j0 += 64) {
        int j = j0 + lane;
        float a = (j < je) ? att_s[j] : -INFINITY;
        m = fmaxf(m, a);
    }
#pragma unroll
    for (int ms = 32; ms; ms >>= 1) m = fmaxf(m, __shfl_xor(m, ms));

    float pl = 0.f, acc = 0.f, acc2 = 0.f;
    for (int j0 = jb; j0 < je; j0 += 64) {
        int j = j0 + lane;
        int cnt = min(64, je - j0);
        float a = (j < je) ? att_s[j] : -INFINITY;
        float p = __expf(a - m);          // inactive lanes: exp(-inf)=0
        int s = (j < je) ? src_s[j] : 0;
        pl += p;
        int jj = 0;
        for (; jj + 3 < cnt; jj += 4) {   // 4 outstanding gathers
            float pj0 = __shfl(p, jj + 0);
            float pj1 = __shfl(p, jj + 1);
            float pj2 = __shfl(p, jj + 2);
            float pj3 = __shfl(p, jj + 3);
            int sj0 = __shfl(s, jj + 0);
            int sj1 = __shfl(s, jj + 1);
            int sj2 = __shfl(s, jj + 2);
            int sj3 = __shfl(s, jj + 3);
            float x0 = nfeat[(size_t)sj0 * DIM + lane];
            float x1 = nfeat[(size_t)sj1 * DIM + lane];
            float x2 = nfeat[(size_t)sj2 * DIM + lane];
            float x3 = nfeat[(size_t)sj3 * DIM + lane];
            acc  = fmaf(pj0, x0, acc);
            acc2 = fmaf(pj1, x1, acc2);
            acc  = fmaf(pj2, x2, acc);
            acc2 = fmaf(pj3, x3, acc2);
        }
        for (; jj < cnt; ++jj) {
            float pj = __shfl(p, jj);
            int sj = __shfl(s, jj);
            acc = fmaf(pj, nfeat[(size_t)sj * DIM + lane], acc);
        }
    }
    acc += acc2;
#pragma unroll
    for (int ms = 32; ms; ms >>= 1) pl += __shfl_xor(pl, ms);

    const float hval = (je > jb) ? acc / pl : 0.f;
    hn[(size_t)node * DIM + lane] = hval;

    const float nf = nfeat[(size_t)node * DIM + lane];
    const float v1 = nf + hval;
    const float v2 = nf * hval;
    float o1 = 0.f, o2 = 0.f;
#pragma unroll 8
    for (int d = 0; d < DIM; ++d) {
        float s1 = __shfl(v1, d);
        float s2 = __shfl(v2, d);
        o1 = fmaf(s1, shW[0][d * DIM + lane], o1);
        o2 = fmaf(s2, shW[1][d * DIM + lane], o2);
    }
    out[(size_t)node * DIM + lane] =
        (o1 >= 0.f ? o1 : 0.01f * o1) + (o2 >= 0.f ? o2 : 0.01f * o2);
}

extern "C" void kernel_launch(void* const* d_in, const int* in_sizes, int n_in,
                              void* d_out, int out_size, void* d_ws, size_t ws_size,
                              hipStream_t stream) {
    const float* nfeat = (const float*)d_in[0];
    const float* efeat = (const float*)d_in[1];
    const float* relW  = (const float*)d_in[2];
    const float* W1    = (const float*)d_in[3];
    const float* W2    = (const float*)d_in[4];
    const int* src   = (const int*)d_in[5];
    const int* dst   = (const int*)d_in[6];
    const int* etype = (const int*)d_in[7];

    const int N = in_sizes[0] / DIM;
    const int E = in_sizes[5];
    const int R = in_sizes[2] / (DIM * DIM);
    const int NB = (N + 255) / 256;   // scan blocks (<=256)

    float* out = (float*)d_out;
    float* hn  = out;
    float* bi  = out + (size_t)N * DIM;

    // ws: proj bf16 | deg[N] | off[N+1] | epart[N] | bsum[256] | rank[E] | src_s[E] | att_s[E]
    unsigned short* proj = (unsigned short*)d_ws;
    size_t projElems = (size_t)R * N * DIM;
    int* deg    = (int*)(proj + projElems);
    int* off    = deg + N;
    int* epart  = off + (N + 1);
    int* bsum   = epart + N;
    int* rank   = bsum + 256;
    int* src_s  = rank + E;
    float* att_s = (float*)(src_s + E);

    (void)hipMemsetAsync(deg, 0, (size_t)N * sizeof(int), stream);

    k_hist<<<(E + 255) / 256, 256, 0, stream>>>(dst, deg, rank, E);
    k_scan1<<<NB, 256, 0, stream>>>(deg, epart, bsum, N);
    k_scan2<<<1, 1024, 0, stream>>>(epart, bsum, NB, off, N, E);

    k_proj<<<(N + 63) / 64, 256, 0, stream>>>(nfeat, relW, proj, N, R);

    k_att<<<((size_t)E * 8 + 255) / 256, 256, 0, stream>>>(proj, efeat, src, dst, etype,
                                                           rank, off, att_s, src_s, N, E);

    k_aggB<<<(N + 3) / 4, 256, 0, stream>>>(att_s, src_s, nfeat, off,
                                            W1, W2, hn, bi, N);
}

// Round 3
// 474.589 us; speedup vs baseline: 1.1973x; 1.1973x over previous
//
#include <hip/hip_runtime.h>
#include <math.h>

// KGATConv: N=50000, E=800000, D=64, R=16, fp32.
// R9: (1) k_aggB split: k_agg = pure softmax+aggregate (no LDS, occupancy up,
//     8 gathers in flight); k_bi = MFMA bi-interaction GEMM (f16 in, f32 acc).
//     The old fused kernel burned 64 serial VALU iterations/wave on a
//     GEMM-shaped op and capped occupancy at 40% with 32KB LDS.
//     (2) k_proj: grid.y=2 (8 relations/block) doubles block-level parallelism
//     of the sync-heavy serial r-loop (was 782 blocks = 3/CU).

#define DIM 64
#define PA 72

typedef _Float16 half8 __attribute__((ext_vector_type(8)));
typedef float f32x4 __attribute__((ext_vector_type(4)));
typedef unsigned int u32x4 __attribute__((ext_vector_type(4)));

__device__ __forceinline__ float4 f4zero() { return make_float4(0.f, 0.f, 0.f, 0.f); }

__device__ __forceinline__ unsigned short f2bf(float x) {
    unsigned u = __float_as_uint(x);
    u += 0x7FFFu + ((u >> 16) & 1u);   // RNE
    return (unsigned short)(u >> 16);
}

__device__ __forceinline__ float fast_tanh(float x) {
    float ex = __expf(2.0f * x);
    return 1.0f - 2.0f / (ex + 1.0f);
}

// unpack 8 bf16 (in a u32x4) to fp32
__device__ __forceinline__ void bf8up(u32x4 u, float* f) {
    f[0] = __uint_as_float(u[0] << 16);
    f[1] = __uint_as_float(u[0] & 0xFFFF0000u);
    f[2] = __uint_as_float(u[1] << 16);
    f[3] = __uint_as_float(u[1] & 0xFFFF0000u);
    f[4] = __uint_as_float(u[2] << 16);
    f[5] = __uint_as_float(u[2] & 0xFFFF0000u);
    f[6] = __uint_as_float(u[3] << 16);
    f[7] = __uint_as_float(u[3] & 0xFFFF0000u);
}

// ---------------------------------------------------------------------------
// proj[r,n,:] = bf16( nfeat[n,:] @ relW[r,:,:] ) via mfma_f32_16x16x32_f16
// A-tile + fragments loaded once; each block loops over R/2 relations
// (blockIdx.y selects the half). Output bounced through LDS -> 16B stores.
// ---------------------------------------------------------------------------
__global__ __launch_bounds__(256) void k_proj(const float* __restrict__ nfeat,
                                              const float* __restrict__ relW,
                                              unsigned short* __restrict__ proj,
                                              int N, int R) {
    __shared__ _Float16 shA[64 * PA];
    __shared__ _Float16 shB[64 * PA];
    unsigned short* shSt = (unsigned short*)shA;   // store-staging (shA dead after frag load)

    const int tx = threadIdx.x;
    const int n0 = blockIdx.x * 64;
    const int rpb = R >> 1;                 // relations per block (grid.y == 2)
    const int rb = blockIdx.y * rpb;

    const float4* nf4 = (const float4*)(nfeat + (size_t)n0 * DIM);
#pragma unroll
    for (int i = 0; i < 4; ++i) {
        int idx = tx + 256 * i;
        int row = idx >> 4, c = idx & 15;
        float4 v = (n0 + row < N) ? nf4[idx] : f4zero();
        _Float16* p = &shA[row * PA + c * 4];
        p[0] = (_Float16)v.x; p[1] = (_Float16)v.y;
        p[2] = (_Float16)v.z; p[3] = (_Float16)v.w;
    }
    __syncthreads();

    const int w = tx >> 6;
    const int lane = tx & 63;
    const int lm = lane & 15;
    const int lq = lane >> 4;
    const int m0 = w * 16;

    // A fragments are relation-independent: load once.
    half8 a0 = *(const half8*)&shA[(m0 + lm) * PA + 0 * 32 + lq * 8];
    half8 a1 = *(const half8*)&shA[(m0 + lm) * PA + 1 * 32 + lq * 8];

    for (int rr = 0; rr < rpb; ++rr) {
        const int r = rb + rr;
        __syncthreads();   // prev iter's shB mfma-reads + shSt store-reads complete
        const float4* Wr4 = (const float4*)(relW + (size_t)r * DIM * DIM);
#pragma unroll
        for (int i = 0; i < 4; ++i) {
            int idx = tx + 256 * i;
            int d = idx >> 4, c = (idx & 15) * 4;
            float4 v = Wr4[idx];
            shB[(c + 0) * PA + d] = (_Float16)v.x;
            shB[(c + 1) * PA + d] = (_Float16)v.y;
            shB[(c + 2) * PA + d] = (_Float16)v.z;
            shB[(c + 3) * PA + d] = (_Float16)v.w;
        }
        __syncthreads();

        f32x4 acc[4];
#pragma unroll
        for (int ct = 0; ct < 4; ++ct) {
            half8 b0 = *(const half8*)&shB[(ct * 16 + lm) * PA + 0 * 32 + lq * 8];
            half8 b1 = *(const half8*)&shB[(ct * 16 + lm) * PA + 1 * 32 + lq * 8];
            f32x4 c = {0.f, 0.f, 0.f, 0.f};
            c = __builtin_amdgcn_mfma_f32_16x16x32_f16(a0, b0, c, 0, 0, 0);
            c = __builtin_amdgcn_mfma_f32_16x16x32_f16(a1, b1, c, 0, 0, 0);
            acc[ct] = c;
        }

        // stage bf16 result in LDS (row stride 72 ushort -> 144B, 16B aligned)
#pragma unroll
        for (int ct = 0; ct < 4; ++ct) {
#pragma unroll
            for (int i = 0; i < 4; ++i) {
                int row = m0 + lq * 4 + i;
                int col = ct * 16 + lm;
                shSt[row * PA + col] = f2bf(acc[ct][i]);
            }
        }
        __syncthreads();

        // coalesced stores: 512 x 16B chunks, 2 per thread; wave covers 1KB
        unsigned short* projR = proj + ((size_t)r * N + n0) * DIM;
#pragma unroll
        for (int k = 0; k < 2; ++k) {
            int chunk = tx + k * 256;
            int row = chunk >> 3, cc = chunk & 7;
            uint4 v = *(const uint4*)&shSt[row * PA + cc * 8];
            if (n0 + row < N)
                *(uint4*)&projR[(size_t)row * DIM + cc * 8] = v;
        }
    }
}

// ---------------------------------------------------------------------------
// CSR build: k_hist's atomic return value is the within-segment rank.
// ---------------------------------------------------------------------------
__global__ __launch_bounds__(256) void k_hist(const int* __restrict__ dst,
                                              int* __restrict__ deg,
                                              int* __restrict__ rank, int E) {
    int e = blockIdx.x * 256 + threadIdx.x;
    if (e < E) rank[e] = atomicAdd(&deg[dst[e]], 1);
}

__global__ __launch_bounds__(256) void k_scan1(const int* __restrict__ deg,
                                               int* __restrict__ epart,
                                               int* __restrict__ bsum, int N) {
    __shared__ int sh[256];
    int i = blockIdx.x * 256 + threadIdx.x;
    int t = threadIdx.x;
    int v = (i < N) ? deg[i] : 0;
    sh[t] = v;
    __syncthreads();
#pragma unroll
    for (int d = 1; d < 256; d <<= 1) {
        int o = (t >= d) ? sh[t - d] : 0;
        __syncthreads();
        sh[t] += o;
        __syncthreads();
    }
    if (i < N) epart[i] = sh[t] - v;
    if (t == 255) bsum[blockIdx.x] = sh[255];
}

__global__ __launch_bounds__(1024) void k_scan2(const int* __restrict__ epart,
                                                const int* __restrict__ bsum,
                                                int nb,
                                                int* __restrict__ off,
                                                int N, int E) {
    __shared__ int bx[256];
    int t = threadIdx.x;
    int v = 0;
    if (t < 256) {
        v = (t < nb) ? bsum[t] : 0;
        bx[t] = v;
    }
    __syncthreads();
#pragma unroll
    for (int d = 1; d < 256; d <<= 1) {
        int o = 0;
        if (t < 256 && t >= d) o = bx[t - d];
        __syncthreads();
        if (t < 256) bx[t] += o;
        __syncthreads();
    }
    if (t < 256) bx[t] -= v;   // exclusive block prefix
    __syncthreads();
    for (int i = t; i < N; i += 1024)
        off[i] = epart[i] + bx[i >> 8];
    if (t == 0) off[N] = E;
}

// ---------------------------------------------------------------------------
// Attention, 8 threads per edge. p = off[dst] + rank (atomic-free slot).
// ---------------------------------------------------------------------------
__global__ __launch_bounds__(256) void k_att(const unsigned short* __restrict__ proj,
                                             const float* __restrict__ efeat,
                                             const int* __restrict__ src,
                                             const int* __restrict__ dst,
                                             const int* __restrict__ etype,
                                             const int* __restrict__ rank,
                                             const int* __restrict__ off,
                                             float* __restrict__ att_s,
                                             int* __restrict__ src_s,
                                             int N, int E) {
    int t = blockIdx.x * 256 + threadIdx.x;
    int e = t >> 3;
    int sub = t & 7;
    if (e >= E) return;
    int s = src[e], d = dst[e], r = etype[e];

    const u32x4* tp = (const u32x4*)(proj + ((size_t)((unsigned)(r * N + s))) * DIM) + sub;
    const u32x4* hp = (const u32x4*)(proj + ((size_t)((unsigned)(r * N + d))) * DIM) + sub;
    const f32x4* ef = (const f32x4*)(efeat + (size_t)e * DIM) + sub * 2;

    u32x4 tu = *tp;
    u32x4 hu = *hp;
    f32x4 efa = __builtin_nontemporal_load(ef);
    f32x4 efb = __builtin_nontemporal_load(ef + 1);

    float tf[8], hf[8];
    bf8up(tu, tf);
    bf8up(hu, hf);
    float ev[8] = {efa[0], efa[1], efa[2], efa[3], efb[0], efb[1], efb[2], efb[3]};

    float dotv = 0.f;
#pragma unroll
    for (int i = 0; i < 8; ++i)
        dotv = fmaf(tf[i], fast_tanh(hf[i] + ev[i]), dotv);

    dotv += __shfl_xor(dotv, 1);
    dotv += __shfl_xor(dotv, 2);
    dotv += __shfl_xor(dotv, 4);

    int p = off[d] + rank[e];
    if (sub == 0) att_s[p] = dotv;
    if (sub == 1) src_s[p] = s;
}

// ---------------------------------------------------------------------------
// Pure softmax + aggregation. Wave per node, NO LDS (max occupancy).
// 8 nfeat row-gathers in flight per wave.
// ---------------------------------------------------------------------------
__global__ __launch_bounds__(256) void k_agg(const float* __restrict__ att_s,
                                             const int* __restrict__ src_s,
                                             const float* __restrict__ nfeat,
                                             const int* __restrict__ off,
                                             float* __restrict__ hn, int N) {
    const int node = blockIdx.x * 4 + (threadIdx.x >> 6);
    if (node >= N) return;
    const int lane = threadIdx.x & 63;

    const int jb = off[node];
    const int je = off[node + 1];

    float m = -INFINITY;
    for (int j0 = jb; j0 < je; j0 += 64) {
        int j = j0 + lane;
        float a = (j < je) ? att_s[j] : -INFINITY;
        m = fmaxf(m, a);
    }
#pragma unroll
    for (int ms = 32; ms; ms >>= 1) m = fmaxf(m, __shfl_xor(m, ms));

    float pl = 0.f;
    float ac0 = 0.f, ac1 = 0.f, ac2 = 0.f, ac3 = 0.f;
    for (int j0 = jb; j0 < je; j0 += 64) {
        int j = j0 + lane;
        int cnt = min(64, je - j0);
        float a = (j < je) ? att_s[j] : -INFINITY;
        float p = __expf(a - m);          // inactive lanes: exp(-inf)=0
        int s = (j < je) ? src_s[j] : 0;
        pl += p;
        int jj = 0;
        for (; jj + 7 < cnt; jj += 8) {   // 8 outstanding gathers
            float pj[8]; int sj[8]; float x[8];
#pragma unroll
            for (int u = 0; u < 8; ++u) {
                pj[u] = __shfl(p, jj + u);
                sj[u] = __shfl(s, jj + u);
            }
#pragma unroll
            for (int u = 0; u < 8; ++u)
                x[u] = nfeat[(size_t)sj[u] * DIM + lane];
            ac0 = fmaf(pj[0], x[0], ac0);
            ac1 = fmaf(pj[1], x[1], ac1);
            ac2 = fmaf(pj[2], x[2], ac2);
            ac3 = fmaf(pj[3], x[3], ac3);
            ac0 = fmaf(pj[4], x[4], ac0);
            ac1 = fmaf(pj[5], x[5], ac1);
            ac2 = fmaf(pj[6], x[6], ac2);
            ac3 = fmaf(pj[7], x[7], ac3);
        }
        for (; jj < cnt; ++jj) {
            float pj = __shfl(p, jj);
            int sj = __shfl(s, jj);
            ac0 = fmaf(pj, nfeat[(size_t)sj * DIM + lane], ac0);
        }
    }
    float acc = (ac0 + ac1) + (ac2 + ac3);
#pragma unroll
    for (int ms = 32; ms; ms >>= 1) pl += __shfl_xor(pl, ms);

    const float hval = (je > jb) ? acc / pl : 0.f;
    hn[(size_t)node * DIM + lane] = hval;
}

// ---------------------------------------------------------------------------
// Bi-interaction: out = lrelu((nf+hn)@W1) + lrelu((nf*hn)@W2), MFMA f16.
// 64 nodes/block, same tile structure as k_proj.
// ---------------------------------------------------------------------------
__global__ __launch_bounds__(256) void k_bi(const float* __restrict__ nfeat,
                                            const float* __restrict__ hn,
                                            const float* __restrict__ W1,
                                            const float* __restrict__ W2,
                                            float* __restrict__ out, int N) {
    __shared__ _Float16 shA1[64 * PA];
    __shared__ _Float16 shA2[64 * PA];
    __shared__ _Float16 shB1[64 * PA];
    __shared__ _Float16 shB2[64 * PA];

    const int tx = threadIdx.x;
    const int n0 = blockIdx.x * 64;

    const float4* nf4 = (const float4*)(nfeat + (size_t)n0 * DIM);
    const float4* hn4 = (const float4*)(hn + (size_t)n0 * DIM);
#pragma unroll
    for (int i = 0; i < 4; ++i) {
        int idx = tx + 256 * i;
        int row = idx >> 4, c = idx & 15;
        bool ok = (n0 + row < N);
        float4 a = ok ? nf4[idx] : f4zero();
        float4 b = ok ? hn4[idx] : f4zero();
        _Float16* p1 = &shA1[row * PA + c * 4];
        _Float16* p2 = &shA2[row * PA + c * 4];
        p1[0] = (_Float16)(a.x + b.x); p2[0] = (_Float16)(a.x * b.x);
        p1[1] = (_Float16)(a.y + b.y); p2[1] = (_Float16)(a.y * b.y);
        p1[2] = (_Float16)(a.z + b.z); p2[2] = (_Float16)(a.z * b.z);
        p1[3] = (_Float16)(a.w + b.w); p2[3] = (_Float16)(a.w * b.w);
    }
    const float4* w14 = (const float4*)W1;
    const float4* w24 = (const float4*)W2;
#pragma unroll
    for (int i = 0; i < 4; ++i) {
        int idx = tx + 256 * i;
        int k = idx >> 4, c = (idx & 15) * 4;
        float4 v = w14[idx];
        shB1[(c + 0) * PA + k] = (_Float16)v.x;
        shB1[(c + 1) * PA + k] = (_Float16)v.y;
        shB1[(c + 2) * PA + k] = (_Float16)v.z;
        shB1[(c + 3) * PA + k] = (_Float16)v.w;
        float4 u = w24[idx];
        shB2[(c + 0) * PA + k] = (_Float16)u.x;
        shB2[(c + 1) * PA + k] = (_Float16)u.y;
        shB2[(c + 2) * PA + k] = (_Float16)u.z;
        shB2[(c + 3) * PA + k] = (_Float16)u.w;
    }
    __syncthreads();

    const int w = tx >> 6;
    const int lane = tx & 63;
    const int lm = lane & 15;
    const int lq = lane >> 4;
    const int m0 = w * 16;

    half8 a10 = *(const half8*)&shA1[(m0 + lm) * PA + 0 * 32 + lq * 8];
    half8 a11 = *(const half8*)&shA1[(m0 + lm) * PA + 1 * 32 + lq * 8];
    half8 a20 = *(const half8*)&shA2[(m0 + lm) * PA + 0 * 32 + lq * 8];
    half8 a21 = *(const half8*)&shA2[(m0 + lm) * PA + 1 * 32 + lq * 8];

    f32x4 res[4];
#pragma unroll
    for (int ct = 0; ct < 4; ++ct) {
        half8 b10 = *(const half8*)&shB1[(ct * 16 + lm) * PA + 0 * 32 + lq * 8];
        half8 b11 = *(const half8*)&shB1[(ct * 16 + lm) * PA + 1 * 32 + lq * 8];
        half8 b20 = *(const half8*)&shB2[(ct * 16 + lm) * PA + 0 * 32 + lq * 8];
        half8 b21 = *(const half8*)&shB2[(ct * 16 + lm) * PA + 1 * 32 + lq * 8];
        f32x4 c1 = {0.f, 0.f, 0.f, 0.f};
        f32x4 c2 = {0.f, 0.f, 0.f, 0.f};
        c1 = __builtin_amdgcn_mfma_f32_16x16x32_f16(a10, b10, c1, 0, 0, 0);
        c1 = __builtin_amdgcn_mfma_f32_16x16x32_f16(a11, b11, c1, 0, 0, 0);
        c2 = __builtin_amdgcn_mfma_f32_16x16x32_f16(a20, b20, c2, 0, 0, 0);
        c2 = __builtin_amdgcn_mfma_f32_16x16x32_f16(a21, b21, c2, 0, 0, 0);
#pragma unroll
        for (int i = 0; i < 4; ++i) {
            float o1 = c1[i], o2 = c2[i];
            res[ct][i] = (o1 >= 0.f ? o1 : 0.01f * o1) + (o2 >= 0.f ? o2 : 0.01f * o2);
        }
    }

    // bounce through LDS (reuse shA1/shA2 as f32 staging, row stride 68)
    __syncthreads();
    float* shSt = (float*)shA1;   // needs 64*68*4 = 17408B <= 2*9216B
#pragma unroll
    for (int ct = 0; ct < 4; ++ct)
#pragma unroll
        for (int i = 0; i < 4; ++i)
            shSt[(m0 + lq * 4 + i) * 68 + ct * 16 + lm] = res[ct][i];
    __syncthreads();

    float* outp = out + (size_t)n0 * DIM;
#pragma unroll
    for (int k = 0; k < 4; ++k) {
        int idx = tx + 256 * k;
        int row = idx >> 4, cc = idx & 15;
        if (n0 + row < N) {
            float4 v = *(const float4*)&shSt[row * 68 + cc * 4];
            *(float4*)&outp[(size_t)row * DIM + cc * 4] = v;
        }
    }
}

extern "C" void kernel_launch(void* const* d_in, const int* in_sizes, int n_in,
                              void* d_out, int out_size, void* d_ws, size_t ws_size,
                              hipStream_t stream) {
    const float* nfeat = (const float*)d_in[0];
    const float* efeat = (const float*)d_in[1];
    const float* relW  = (const float*)d_in[2];
    const float* W1    = (const float*)d_in[3];
    const float* W2    = (const float*)d_in[4];
    const int* src   = (const int*)d_in[5];
    const int* dst   = (const int*)d_in[6];
    const int* etype = (const int*)d_in[7];

    const int N = in_sizes[0] / DIM;
    const int E = in_sizes[5];
    const int R = in_sizes[2] / (DIM * DIM);
    const int NB = (N + 255) / 256;   // scan blocks (<=256)

    float* out = (float*)d_out;
    float* hn  = out;
    float* bi  = out + (size_t)N * DIM;

    // ws: proj bf16 | deg[N] | off[N+1] | epart[N] | bsum[256] | rank[E] | src_s[E] | att_s[E]
    unsigned short* proj = (unsigned short*)d_ws;
    size_t projElems = (size_t)R * N * DIM;
    int* deg    = (int*)(proj + projElems);
    int* off    = deg + N;
    int* epart  = off + (N + 1);
    int* bsum   = epart + N;
    int* rank   = bsum + 256;
    int* src_s  = rank + E;
    float* att_s = (float*)(src_s + E);

    (void)hipMemsetAsync(deg, 0, (size_t)N * sizeof(int), stream);

    k_hist<<<(E + 255) / 256, 256, 0, stream>>>(dst, deg, rank, E);
    k_scan1<<<NB, 256, 0, stream>>>(deg, epart, bsum, N);
    k_scan2<<<1, 1024, 0, stream>>>(epart, bsum, NB, off, N, E);

    dim3 gProj((N + 63) / 64, 2);
    k_proj<<<gProj, 256, 0, stream>>>(nfeat, relW, proj, N, R);

    k_att<<<((size_t)E * 8 + 255) / 256, 256, 0, stream>>>(proj, efeat, src, dst, etype,
                                                           rank, off, att_s, src_s, N, E);

    k_agg<<<(N + 3) / 4, 256, 0, stream>>>(att_s, src_s, nfeat, off, hn, N);

    k_bi<<<(N + 63) / 64, 256, 0, stream>>>(nfeat, hn, W1, W2, bi, N);
}

// Round 4
// 468.671 us; speedup vs baseline: 1.2124x; 1.0126x over previous
//
#include <hip/hip_runtime.h>
#include <math.h>

// KGATConv: N=50000, E=800000, D=64, R=16, fp32.
// R10: (1) k_agg gather restructured to quarter-wave float4 rows: one VMEM
//     instruction fetches 4 nfeat rows (16 lanes x 16B each), unroll 4 ->
//     16 rows in flight (whole avg-degree-16 node in one burst). Cross-
//     quarter f32x4 reduce via shfl_xor(16,32).
//     (2) k_proj grid.y=4 (4 relations/block, 12 blocks/CU).
//     (3) k_bi LDS aliasing made explicit (single shared block).

#define DIM 64
#define PA 72

typedef _Float16 half8 __attribute__((ext_vector_type(8)));
typedef float f32x4 __attribute__((ext_vector_type(4)));
typedef unsigned int u32x4 __attribute__((ext_vector_type(4)));

__device__ __forceinline__ float4 f4zero() { return make_float4(0.f, 0.f, 0.f, 0.f); }

__device__ __forceinline__ unsigned short f2bf(float x) {
    unsigned u = __float_as_uint(x);
    u += 0x7FFFu + ((u >> 16) & 1u);   // RNE
    return (unsigned short)(u >> 16);
}

__device__ __forceinline__ float fast_tanh(float x) {
    float ex = __expf(2.0f * x);
    return 1.0f - 2.0f / (ex + 1.0f);
}

// unpack 8 bf16 (in a u32x4) to fp32
__device__ __forceinline__ void bf8up(u32x4 u, float* f) {
    f[0] = __uint_as_float(u[0] << 16);
    f[1] = __uint_as_float(u[0] & 0xFFFF0000u);
    f[2] = __uint_as_float(u[1] << 16);
    f[3] = __uint_as_float(u[1] & 0xFFFF0000u);
    f[4] = __uint_as_float(u[2] << 16);
    f[5] = __uint_as_float(u[2] & 0xFFFF0000u);
    f[6] = __uint_as_float(u[3] << 16);
    f[7] = __uint_as_float(u[3] & 0xFFFF0000u);
}

// ---------------------------------------------------------------------------
// proj[r,n,:] = bf16( nfeat[n,:] @ relW[r,:,:] ) via mfma_f32_16x16x32_f16
// A-tile + fragments loaded once; each block loops over R/4 relations
// (blockIdx.y selects the quarter). Output bounced through LDS -> 16B stores.
// ---------------------------------------------------------------------------
__global__ __launch_bounds__(256) void k_proj(const float* __restrict__ nfeat,
                                              const float* __restrict__ relW,
                                              unsigned short* __restrict__ proj,
                                              int N, int R) {
    __shared__ _Float16 shA[64 * PA];
    __shared__ _Float16 shB[64 * PA];
    unsigned short* shSt = (unsigned short*)shA;   // store-staging (shA dead after frag load)

    const int tx = threadIdx.x;
    const int n0 = blockIdx.x * 64;
    const int rpb = R >> 2;                 // relations per block (grid.y == 4)
    const int rb = blockIdx.y * rpb;

    const float4* nf4 = (const float4*)(nfeat + (size_t)n0 * DIM);
#pragma unroll
    for (int i = 0; i < 4; ++i) {
        int idx = tx + 256 * i;
        int row = idx >> 4, c = idx & 15;
        float4 v = (n0 + row < N) ? nf4[idx] : f4zero();
        _Float16* p = &shA[row * PA + c * 4];
        p[0] = (_Float16)v.x; p[1] = (_Float16)v.y;
        p[2] = (_Float16)v.z; p[3] = (_Float16)v.w;
    }
    __syncthreads();

    const int w = tx >> 6;
    const int lane = tx & 63;
    const int lm = lane & 15;
    const int lq = lane >> 4;
    const int m0 = w * 16;

    // A fragments are relation-independent: load once.
    half8 a0 = *(const half8*)&shA[(m0 + lm) * PA + 0 * 32 + lq * 8];
    half8 a1 = *(const half8*)&shA[(m0 + lm) * PA + 1 * 32 + lq * 8];

    for (int rr = 0; rr < rpb; ++rr) {
        const int r = rb + rr;
        __syncthreads();   // prev iter's shB mfma-reads + shSt store-reads complete
        const float4* Wr4 = (const float4*)(relW + (size_t)r * DIM * DIM);
#pragma unroll
        for (int i = 0; i < 4; ++i) {
            int idx = tx + 256 * i;
            int d = idx >> 4, c = (idx & 15) * 4;
            float4 v = Wr4[idx];
            shB[(c + 0) * PA + d] = (_Float16)v.x;
            shB[(c + 1) * PA + d] = (_Float16)v.y;
            shB[(c + 2) * PA + d] = (_Float16)v.z;
            shB[(c + 3) * PA + d] = (_Float16)v.w;
        }
        __syncthreads();

        f32x4 acc[4];
#pragma unroll
        for (int ct = 0; ct < 4; ++ct) {
            half8 b0 = *(const half8*)&shB[(ct * 16 + lm) * PA + 0 * 32 + lq * 8];
            half8 b1 = *(const half8*)&shB[(ct * 16 + lm) * PA + 1 * 32 + lq * 8];
            f32x4 c = {0.f, 0.f, 0.f, 0.f};
            c = __builtin_amdgcn_mfma_f32_16x16x32_f16(a0, b0, c, 0, 0, 0);
            c = __builtin_amdgcn_mfma_f32_16x16x32_f16(a1, b1, c, 0, 0, 0);
            acc[ct] = c;
        }

        // stage bf16 result in LDS (row stride 72 ushort -> 144B, 16B aligned)
#pragma unroll
        for (int ct = 0; ct < 4; ++ct) {
#pragma unroll
            for (int i = 0; i < 4; ++i) {
                int row = m0 + lq * 4 + i;
                int col = ct * 16 + lm;
                shSt[row * PA + col] = f2bf(acc[ct][i]);
            }
        }
        __syncthreads();

        // coalesced stores: 512 x 16B chunks, 2 per thread; wave covers 1KB
        unsigned short* projR = proj + ((size_t)r * N + n0) * DIM;
#pragma unroll
        for (int k = 0; k < 2; ++k) {
            int chunk = tx + k * 256;
            int row = chunk >> 3, cc = chunk & 7;
            uint4 v = *(const uint4*)&shSt[row * PA + cc * 8];
            if (n0 + row < N)
                *(uint4*)&projR[(size_t)row * DIM + cc * 8] = v;
        }
    }
}

// ---------------------------------------------------------------------------
// CSR build: k_hist's atomic return value is the within-segment rank.
// ---------------------------------------------------------------------------
__global__ __launch_bounds__(256) void k_hist(const int* __restrict__ dst,
                                              int* __restrict__ deg,
                                              int* __restrict__ rank, int E) {
    int e = blockIdx.x * 256 + threadIdx.x;
    if (e < E) rank[e] = atomicAdd(&deg[dst[e]], 1);
}

__global__ __launch_bounds__(256) void k_scan1(const int* __restrict__ deg,
                                               int* __restrict__ epart,
                                               int* __restrict__ bsum, int N) {
    __shared__ int sh[256];
    int i = blockIdx.x * 256 + threadIdx.x;
    int t = threadIdx.x;
    int v = (i < N) ? deg[i] : 0;
    sh[t] = v;
    __syncthreads();
#pragma unroll
    for (int d = 1; d < 256; d <<= 1) {
        int o = (t >= d) ? sh[t - d] : 0;
        __syncthreads();
        sh[t] += o;
        __syncthreads();
    }
    if (i < N) epart[i] = sh[t] - v;
    if (t == 255) bsum[blockIdx.x] = sh[255];
}

__global__ __launch_bounds__(1024) void k_scan2(const int* __restrict__ epart,
                                                const int* __restrict__ bsum,
                                                int nb,
                                                int* __restrict__ off,
                                                int N, int E) {
    __shared__ int bx[256];
    int t = threadIdx.x;
    int v = 0;
    if (t < 256) {
        v = (t < nb) ? bsum[t] : 0;
        bx[t] = v;
    }
    __syncthreads();
#pragma unroll
    for (int d = 1; d < 256; d <<= 1) {
        int o = 0;
        if (t < 256 && t >= d) o = bx[t - d];
        __syncthreads();
        if (t < 256) bx[t] += o;
        __syncthreads();
    }
    if (t < 256) bx[t] -= v;   // exclusive block prefix
    __syncthreads();
    for (int i = t; i < N; i += 1024)
        off[i] = epart[i] + bx[i >> 8];
    if (t == 0) off[N] = E;
}

// ---------------------------------------------------------------------------
// Attention, 8 threads per edge. p = off[dst] + rank (atomic-free slot).
// ---------------------------------------------------------------------------
__global__ __launch_bounds__(256) void k_att(const unsigned short* __restrict__ proj,
                                             const float* __restrict__ efeat,
                                             const int* __restrict__ src,
                                             const int* __restrict__ dst,
                                             const int* __restrict__ etype,
                                             const int* __restrict__ rank,
                                             const int* __restrict__ off,
                                             float* __restrict__ att_s,
                                             int* __restrict__ src_s,
                                             int N, int E) {
    int t = blockIdx.x * 256 + threadIdx.x;
    int e = t >> 3;
    int sub = t & 7;
    if (e >= E) return;
    int s = src[e], d = dst[e], r = etype[e];

    const u32x4* tp = (const u32x4*)(proj + ((size_t)((unsigned)(r * N + s))) * DIM) + sub;
    const u32x4* hp = (const u32x4*)(proj + ((size_t)((unsigned)(r * N + d))) * DIM) + sub;
    const f32x4* ef = (const f32x4*)(efeat + (size_t)e * DIM) + sub * 2;

    u32x4 tu = *tp;
    u32x4 hu = *hp;
    f32x4 efa = __builtin_nontemporal_load(ef);
    f32x4 efb = __builtin_nontemporal_load(ef + 1);

    float tf[8], hf[8];
    bf8up(tu, tf);
    bf8up(hu, hf);
    float ev[8] = {efa[0], efa[1], efa[2], efa[3], efb[0], efb[1], efb[2], efb[3]};

    float dotv = 0.f;
#pragma unroll
    for (int i = 0; i < 8; ++i)
        dotv = fmaf(tf[i], fast_tanh(hf[i] + ev[i]), dotv);

    dotv += __shfl_xor(dotv, 1);
    dotv += __shfl_xor(dotv, 2);
    dotv += __shfl_xor(dotv, 4);

    int p = off[d] + rank[e];
    if (sub == 0) att_s[p] = dotv;
    if (sub == 1) src_s[p] = s;
}

// ---------------------------------------------------------------------------
// Pure softmax + aggregation. Wave per node, NO LDS.
// Gather: quarter-wave float4 rows -- one VMEM instruction covers 4 nfeat
// rows (16 lanes x 16B), unroll 4 -> 16 rows in flight per wave.
// ---------------------------------------------------------------------------
__global__ __launch_bounds__(256) void k_agg(const float* __restrict__ att_s,
                                             const int* __restrict__ src_s,
                                             const float* __restrict__ nfeat,
                                             const int* __restrict__ off,
                                             float* __restrict__ hn, int N) {
    const int node = blockIdx.x * 4 + (threadIdx.x >> 6);
    if (node >= N) return;
    const int lane = threadIdx.x & 63;
    const int qw = lane >> 4;   // quarter-wave index 0..3 (row slot)
    const int ql = lane & 15;   // lane within quarter   (4-dim slice)

    const int jb = off[node];
    const int je = off[node + 1];

    // segment max (edge-parallel, coalesced)
    float m = -INFINITY;
    for (int j0 = jb; j0 < je; j0 += 64) {
        int j = j0 + lane;
        float a = (j < je) ? att_s[j] : -INFINITY;
        m = fmaxf(m, a);
    }
#pragma unroll
    for (int ms = 32; ms; ms >>= 1) m = fmaxf(m, __shfl_xor(m, ms));

    float pl = 0.f;
    f32x4 acc = {0.f, 0.f, 0.f, 0.f};
    for (int j0 = jb; j0 < je; j0 += 64) {
        int j = j0 + lane;
        int cnt = min(64, je - j0);
        float a = (j < je) ? att_s[j] : -INFINITY;
        float p = __expf(a - m);          // inactive lanes: exp(-inf)=0
        int s = (j < je) ? src_s[j] : 0;
        pl += p;

        int jj = 0;
        for (; jj + 15 < cnt; jj += 16) {   // 16 rows in flight
            float pj[4]; int sj[4]; f32x4 x[4];
#pragma unroll
            for (int u = 0; u < 4; ++u) {
                int eidx = jj + u * 4 + qw;
                pj[u] = __shfl(p, eidx);
                sj[u] = __shfl(s, eidx);
            }
#pragma unroll
            for (int u = 0; u < 4; ++u)
                x[u] = *(const f32x4*)&nfeat[(size_t)sj[u] * DIM + ql * 4];
#pragma unroll
            for (int u = 0; u < 4; ++u) {
                acc[0] = fmaf(pj[u], x[u][0], acc[0]);
                acc[1] = fmaf(pj[u], x[u][1], acc[1]);
                acc[2] = fmaf(pj[u], x[u][2], acc[2]);
                acc[3] = fmaf(pj[u], x[u][3], acc[3]);
            }
        }
        for (; jj < cnt; jj += 4) {         // remainder: 4 rows at a time
            int eidx = jj + qw;
            int ec = (eidx < cnt) ? eidx : (cnt - 1);
            float pj = __shfl(p, ec);
            int sj = __shfl(s, ec);
            if (eidx < cnt) {
                f32x4 x = *(const f32x4*)&nfeat[(size_t)sj * DIM + ql * 4];
                acc[0] = fmaf(pj, x[0], acc[0]);
                acc[1] = fmaf(pj, x[1], acc[1]);
                acc[2] = fmaf(pj, x[2], acc[2]);
                acc[3] = fmaf(pj, x[3], acc[3]);
            }
        }
    }
#pragma unroll
    for (int ms = 32; ms; ms >>= 1) pl += __shfl_xor(pl, ms);

    // combine the 4 quarter-partials: lanes {ql, ql+16, ql+32, ql+48}
#pragma unroll
    for (int c = 0; c < 4; ++c) {
        acc[c] += __shfl_xor(acc[c], 16);
        acc[c] += __shfl_xor(acc[c], 32);
    }

    const float inv = (je > jb) ? 1.0f / pl : 0.f;
    if (qw == 0) {
        f32x4 hv = {acc[0] * inv, acc[1] * inv, acc[2] * inv, acc[3] * inv};
        *(f32x4*)&hn[(size_t)node * DIM + ql * 4] = hv;
    }
}

// ---------------------------------------------------------------------------
// Bi-interaction: out = lrelu((nf+hn)@W1) + lrelu((nf*hn)@W2), MFMA f16.
// 64 nodes/block, same tile structure as k_proj.
// ---------------------------------------------------------------------------
__global__ __launch_bounds__(256) void k_bi(const float* __restrict__ nfeat,
                                            const float* __restrict__ hn,
                                            const float* __restrict__ W1,
                                            const float* __restrict__ W2,
                                            float* __restrict__ out, int N) {
    __shared__ _Float16 shMem[4 * 64 * PA];
    _Float16* shA1 = shMem;
    _Float16* shA2 = shMem + 64 * PA;
    _Float16* shB1 = shMem + 2 * 64 * PA;
    _Float16* shB2 = shMem + 3 * 64 * PA;

    const int tx = threadIdx.x;
    const int n0 = blockIdx.x * 64;

    const float4* nf4 = (const float4*)(nfeat + (size_t)n0 * DIM);
    const float4* hn4 = (const float4*)(hn + (size_t)n0 * DIM);
#pragma unroll
    for (int i = 0; i < 4; ++i) {
        int idx = tx + 256 * i;
        int row = idx >> 4, c = idx & 15;
        bool ok = (n0 + row < N);
        float4 a = ok ? nf4[idx] : f4zero();
        float4 b = ok ? hn4[idx] : f4zero();
        _Float16* p1 = &shA1[row * PA + c * 4];
        _Float16* p2 = &shA2[row * PA + c * 4];
        p1[0] = (_Float16)(a.x + b.x); p2[0] = (_Float16)(a.x * b.x);
        p1[1] = (_Float16)(a.y + b.y); p2[1] = (_Float16)(a.y * b.y);
        p1[2] = (_Float16)(a.z + b.z); p2[2] = (_Float16)(a.z * b.z);
        p1[3] = (_Float16)(a.w + b.w); p2[3] = (_Float16)(a.w * b.w);
    }
    const float4* w14 = (const float4*)W1;
    const float4* w24 = (const float4*)W2;
#pragma unroll
    for (int i = 0; i < 4; ++i) {
        int idx = tx + 256 * i;
        int k = idx >> 4, c = (idx & 15) * 4;
        float4 v = w14[idx];
        shB1[(c + 0) * PA + k] = (_Float16)v.x;
        shB1[(c + 1) * PA + k] = (_Float16)v.y;
        shB1[(c + 2) * PA + k] = (_Float16)v.z;
        shB1[(c + 3) * PA + k] = (_Float16)v.w;
        float4 u = w24[idx];
        shB2[(c + 0) * PA + k] = (_Float16)u.x;
        shB2[(c + 1) * PA + k] = (_Float16)u.y;
        shB2[(c + 2) * PA + k] = (_Float16)u.z;
        shB2[(c + 3) * PA + k] = (_Float16)u.w;
    }
    __syncthreads();

    const int w = tx >> 6;
    const int lane = tx & 63;
    const int lm = lane & 15;
    const int lq = lane >> 4;
    const int m0 = w * 16;

    half8 a10 = *(const half8*)&shA1[(m0 + lm) * PA + 0 * 32 + lq * 8];
    half8 a11 = *(const half8*)&shA1[(m0 + lm) * PA + 1 * 32 + lq * 8];
    half8 a20 = *(const half8*)&shA2[(m0 + lm) * PA + 0 * 32 + lq * 8];
    half8 a21 = *(const half8*)&shA2[(m0 + lm) * PA + 1 * 32 + lq * 8];

    f32x4 res[4];
#pragma unroll
    for (int ct = 0; ct < 4; ++ct) {
        half8 b10 = *(const half8*)&shB1[(ct * 16 + lm) * PA + 0 * 32 + lq * 8];
        half8 b11 = *(const half8*)&shB1[(ct * 16 + lm) * PA + 1 * 32 + lq * 8];
        half8 b20 = *(const half8*)&shB2[(ct * 16 + lm) * PA + 0 * 32 + lq * 8];
        half8 b21 = *(const half8*)&shB2[(ct * 16 + lm) * PA + 1 * 32 + lq * 8];
        f32x4 c1 = {0.f, 0.f, 0.f, 0.f};
        f32x4 c2 = {0.f, 0.f, 0.f, 0.f};
        c1 = __builtin_amdgcn_mfma_f32_16x16x32_f16(a10, b10, c1, 0, 0, 0);
        c1 = __builtin_amdgcn_mfma_f32_16x16x32_f16(a11, b11, c1, 0, 0, 0);
        c2 = __builtin_amdgcn_mfma_f32_16x16x32_f16(a20, b20, c2, 0, 0, 0);
        c2 = __builtin_amdgcn_mfma_f32_16x16x32_f16(a21, b21, c2, 0, 0, 0);
#pragma unroll
        for (int i = 0; i < 4; ++i) {
            float o1 = c1[i], o2 = c2[i];
            res[ct][i] = (o1 >= 0.f ? o1 : 0.01f * o1) + (o2 >= 0.f ? o2 : 0.01f * o2);
        }
    }

    // bounce through LDS (f32 staging in shMem, row stride 68 floats)
    __syncthreads();
    float* shSt = (float*)shMem;   // 64*68*4 = 17408B <= 4*64*PA*2 = 36864B
#pragma unroll
    for (int ct = 0; ct < 4; ++ct)
#pragma unroll
        for (int i = 0; i < 4; ++i)
            shSt[(m0 + lq * 4 + i) * 68 + ct * 16 + lm] = res[ct][i];
    __syncthreads();

    float* outp = out + (size_t)n0 * DIM;
#pragma unroll
    for (int k = 0; k < 4; ++k) {
        int idx = tx + 256 * k;
        int row = idx >> 4, cc = idx & 15;
        if (n0 + row < N) {
            float4 v = *(const float4*)&shSt[row * 68 + cc * 4];
            *(float4*)&outp[(size_t)row * DIM + cc * 4] = v;
        }
    }
}

extern "C" void kernel_launch(void* const* d_in, const int* in_sizes, int n_in,
                              void* d_out, int out_size, void* d_ws, size_t ws_size,
                              hipStream_t stream) {
    const float* nfeat = (const float*)d_in[0];
    const float* efeat = (const float*)d_in[1];
    const float* relW  = (const float*)d_in[2];
    const float* W1    = (const float*)d_in[3];
    const float* W2    = (const float*)d_in[4];
    const int* src   = (const int*)d_in[5];
    const int* dst   = (const int*)d_in[6];
    const int* etype = (const int*)d_in[7];

    const int N = in_sizes[0] / DIM;
    const int E = in_sizes[5];
    const int R = in_sizes[2] / (DIM * DIM);
    const int NB = (N + 255) / 256;   // scan blocks (<=256)

    float* out = (float*)d_out;
    float* hn  = out;
    float* bi  = out + (size_t)N * DIM;

    // ws: proj bf16 | deg[N] | off[N+1] | epart[N] | bsum[256] | rank[E] | src_s[E] | att_s[E]
    unsigned short* proj = (unsigned short*)d_ws;
    size_t projElems = (size_t)R * N * DIM;
    int* deg    = (int*)(proj + projElems);
    int* off    = deg + N;
    int* epart  = off + (N + 1);
    int* bsum   = epart + N;
    int* rank   = bsum + 256;
    int* src_s  = rank + E;
    float* att_s = (float*)(src_s + E);

    (void)hipMemsetAsync(deg, 0, (size_t)N * sizeof(int), stream);

    k_hist<<<(E + 255) / 256, 256, 0, stream>>>(dst, deg, rank, E);
    k_scan1<<<NB, 256, 0, stream>>>(deg, epart, bsum, N);
    k_scan2<<<1, 1024, 0, stream>>>(epart, bsum, NB, off, N, E);

    dim3 gProj((N + 63) / 64, 4);
    k_proj<<<gProj, 256, 0, stream>>>(nfeat, relW, proj, N, R);

    k_att<<<((size_t)E * 8 + 255) / 256, 256, 0, stream>>>(proj, efeat, src, dst, etype,
                                                           rank, off, att_s, src_s, N, E);

    k_agg<<<(N + 3) / 4, 256, 0, stream>>>(att_s, src_s, nfeat, off, hn, N);

    k_bi<<<(N + 63) / 64, 256, 0, stream>>>(nfeat, hn, W1, W2, bi, N);
}